// Round 9
// baseline (238.779 us; speedup 1.0000x reference)
//
#include <hip/hip_runtime.h>

#define NKW   65536
#define NDOC  65536
#define NSEG  131072
#define NE    1048576
#define CHUNK 4096
#define NBLK  (NE / CHUNK)    // 256

typedef unsigned long long u64;
typedef unsigned short     u16;
typedef unsigned int       u32;

typedef __attribute__((ext_vector_type(8))) short short8;   // 8 bf16
typedef __attribute__((ext_vector_type(4))) float f32x4;    // MFMA acc

union U8 { short8 v; u64 u[2]; short s[8]; };

__device__ __forceinline__ u16 f2bf(float f) {              // RNE f32->bf16
    u32 u = __builtin_bit_cast(u32, f);
    u = (u + 0x7fffu + ((u >> 16) & 1u)) >> 16;
    return (u16)u;
}
__device__ __forceinline__ float bf2f(u16 h) {
    return __builtin_bit_cast(float, (u32)h << 16);
}

// ---------------- workspace layout (bytes) ----------------
// bufA: h0 bf16. bufB: g = xf*xt bf16. bufC: pairs (CSR build) then xdoc bf16.
#define BUFA_OFF 0ull
#define BUFB_OFF 16777216ull
#define BUFC_OFF 33554432ull
#define WF_OFF   50331648ull            // 7 * 32KB fragment-packed weights
#define CSR_OFF  51380224ull            // 2*NE ints = 8 MB
#define CNT_OFF  59768832ull            // NSEG ints
#define AUX_OFF  60293120ull            // bhist[512] | bfill[512]
#define OFF_OFF  60821504ull            // NSEG ints
#define DIS_OFF  61345792ull            // NSEG floats

struct PrepArgs { const float* w[7]; int K[7]; };

// ================= K1: bucket histogram (blocks 0..255) + weight pre-pack =======
__global__ __launch_bounds__(256) void k1_hist_prep(
        const int* __restrict__ src, const int* __restrict__ dst,
        int* __restrict__ bhist, PrepArgs pa, short8* __restrict__ wfb) {
    __shared__ int h[512];
    const int tid = threadIdx.x;
    if (blockIdx.x < NBLK) {
        for (int i = tid; i < 512; i += 256) h[i] = 0;
        __syncthreads();
        int e0 = blockIdx.x * CHUNK;
        for (int i = tid; i < CHUNK; i += 256) {
            int s = src[e0 + i];
            int d = dst[e0 + i] - NKW;
            atomicAdd(&h[s >> 8], 1);
            atomicAdd(&h[256 + (d >> 8)], 1);
        }
        __syncthreads();
        for (int i = tid; i < 512; i += 256)
            if (h[i]) atomicAdd(&bhist[i], h[i]);
    } else {
        int u = (blockIdx.x - NBLK) * 4 + (tid >> 6);   // prepw unit 0..223
        if (u < 224) {
            int m = u >> 5, bk = u & 31;
            int kc = bk >> 3, ct = bk & 7;
            int l = tid & 63;
            int K = pa.K[m];
            const float* W = pa.w[m];
            U8 o;
            #pragma unroll
            for (int i = 0; i < 8; ++i) {
                int k   = kc * 32 + 4 * (l >> 4) + (i & 3) + 16 * (i >> 2);
                int col = ct * 16 + (l & 15);
                float v = (k < K) ? W[(size_t)k * 128 + col] : 0.f;
                o.s[i] = (short)f2bf(v);
            }
            wfb[(size_t)m * 2048 + bk * 64 + l] = o.v;
        }
    }
}

// ================= K2: edge partition (inline global-base scan) =================
__global__ __launch_bounds__(256) void k2_part(
        const int* __restrict__ src, const int* __restrict__ dst,
        const int* __restrict__ bhist, int* __restrict__ bfill,
        u32* __restrict__ pairs) {
    __shared__ int h[512], sc[512], base[512], gb[512];
    __shared__ u32 staged[2 * CHUNK];
    const int tid = threadIdx.x;

    // inclusive scan of bhist -> gb, then make exclusive
    for (int i = tid; i < 512; i += 256) gb[i] = bhist[i];
    __syncthreads();
    for (int d = 1; d < 512; d <<= 1) {
        int i1 = tid + 256;
        int t0 = (tid >= d) ? gb[tid - d] : 0;
        int t1 = gb[i1 - d];
        __syncthreads();
        gb[tid] += t0; gb[i1] += t1;
        __syncthreads();
    }
    for (int i = tid; i < 512; i += 256) gb[i] -= bhist[i];   // exclusive base
    for (int i = tid; i < 512; i += 256) h[i] = 0;
    __syncthreads();

    const int e0 = blockIdx.x * CHUNK;
    int se[16], de[16];
    #pragma unroll
    for (int j = 0; j < 16; ++j) {
        int e = e0 + tid + j * 256;
        se[j] = src[e];
        de[j] = dst[e] - NKW;
        atomicAdd(&h[se[j] >> 8], 1);
        atomicAdd(&h[256 + (de[j] >> 8)], 1);
    }
    __syncthreads();

    sc[tid] = h[tid];
    __syncthreads();
    for (int d = 1; d < 256; d <<= 1) {
        int t = (tid >= d) ? sc[tid - d] : 0;
        __syncthreads();
        sc[tid] += t;
        __syncthreads();
    }
    sc[256 + tid] = h[256 + tid];
    __syncthreads();
    for (int d = 1; d < 256; d <<= 1) {
        int t = (tid >= d) ? sc[256 + tid - d] : 0;
        __syncthreads();
        sc[256 + tid] += t;
        __syncthreads();
    }

    for (int i = tid; i < 512; i += 256) {
        base[i] = gb[i] + atomicAdd(&bfill[i], h[i]);
        sc[i] -= h[i];
        h[i] = 0;
    }
    __syncthreads();

    #pragma unroll
    for (int j = 0; j < 16; ++j) {
        int bk = se[j] >> 8;
        int r  = atomicAdd(&h[bk], 1);
        staged[sc[bk] + r] = ((u32)(se[j] & 255) << 16) | (u32)de[j];
        int bd = 256 + (de[j] >> 8);
        int r2 = atomicAdd(&h[bd], 1);
        staged[CHUNK + sc[bd] + r2] = ((u32)(de[j] & 255) << 16) | (u32)se[j];
    }
    __syncthreads();

    for (int i = tid; i < 512; i += 256) {
        int n = h[i];
        int so = (i < 256 ? 0 : CHUNK) + sc[i];
        u32* dp = pairs + base[i];
        for (int j = 0; j < n; ++j) dp[j] = staged[so + j];
    }
}

// ================= K3: CSR build (0..511) | mgemm0 (512..1535) | gatesPre =======
__global__ __launch_bounds__(256, 4) void k3_build_gemm_gates(
        const u32* __restrict__ pairs, const int* __restrict__ bhist,
        int* __restrict__ off, int* __restrict__ cnt, float* __restrict__ dis,
        int* __restrict__ csr,
        const float* __restrict__ Xn, const short8* __restrict__ wfb,
        const float* __restrict__ b0, u16* __restrict__ bufA,
        const float* __restrict__ Xfb, const float* __restrict__ Xt,
        const float* __restrict__ bf1v, const float* __restrict__ bf2v,
        const float* __restrict__ bt1v, const float* __restrict__ bt2v,
        u16* __restrict__ gbuf) {
    __shared__ int S[2816];    // lcnt[1024] | loff[1024] | bs[256] | gsc[512]
    const int tid = threadIdx.x;

    if (blockIdx.x < 512) {
        // ---- CSR build with per-node counting sort ----
        int* lcnt = S;
        int* loff = S + 1024;
        int* bs   = S + 2048;
        int* gsc  = S + 2304;
        const int b = blockIdx.x;
        for (int i = tid; i < 512; i += 256) gsc[i] = bhist[i];
        __syncthreads();
        for (int d = 1; d < 512; d <<= 1) {
            int i1 = tid + 256;
            int t0 = (tid >= d) ? gsc[tid - d] : 0;
            int t1 = gsc[i1 - d];
            __syncthreads();
            gsc[tid] += t0; gsc[i1] += t1;
            __syncthreads();
        }
        const int size  = bhist[b];
        const int start = gsc[b] - size;      // exclusive
        for (int i = tid; i < 1024; i += 256) lcnt[i] = 0;
        __syncthreads();
        for (int i = tid; i < size; i += 256) {
            u32 p = __builtin_nontemporal_load(pairs + start + i);
            atomicAdd(&lcnt[(p >> 16) & 255], 1);
        }
        __syncthreads();
        int s = lcnt[tid];
        bs[tid] = s;
        __syncthreads();
        for (int d = 1; d < 256; d <<= 1) {
            int t = (tid >= d) ? bs[tid - d] : 0;
            __syncthreads();
            bs[tid] += t;
            __syncthreads();
        }
        const int P = bs[tid] - s;
        const int seg = (b < 256) ? (b * 256 + tid) : (NKW + (b - 256) * 256 + tid);
        off[seg] = start + P;
        cnt[seg] = s;
        dis[seg] = rsqrtf((float)(s + 1));
        loff[tid] = P;
        lcnt[tid] = 0;
        __syncthreads();
        for (int i = tid; i < size; i += 256) {
            u32 p = __builtin_nontemporal_load(pairs + start + i);
            int key = (p >> 16) & 255;
            int r = atomicAdd(&lcnt[key], 1);
            csr[start + loff[key] + r] = (int)(p & 0xFFFF);
        }
    } else if (blockIdx.x < 1536) {
        // ---- layer 0: h0 = relu(Xn @ W0 + b0), fp32 in, bf16 out ----
        const int blk = blockIdx.x - 512;
        const int w = tid >> 6, l = tid & 63, lr = l & 15, q = l >> 4;
        const int row = blk * 64 + w * 16 + lr;
        f32x4 acc[8];
        #pragma unroll
        for (int ct = 0; ct < 8; ++ct) acc[ct] = (f32x4){0.f, 0.f, 0.f, 0.f};
        #pragma unroll
        for (int kc = 0; kc < 4; ++kc) {
            U8 a;
            const int kb = kc * 32 + 4 * q;
            const float* A = Xn + (size_t)row * 128;
            f32x4 lo = *(const f32x4*)(A + kb);
            f32x4 hi = *(const f32x4*)(A + kb + 16);
            #pragma unroll
            for (int i = 0; i < 4; ++i) {
                a.s[i]     = (short)f2bf(lo[i]);
                a.s[4 + i] = (short)f2bf(hi[i]);
            }
            #pragma unroll
            for (int ct = 0; ct < 8; ++ct)
                acc[ct] = __builtin_amdgcn_mfma_f32_16x16x32_bf16(
                              a.v, wfb[(kc * 8 + ct) * 64 + l], acc[ct], 0, 0, 0);
        }
        const int orow0 = blk * 64 + w * 16 + 4 * q;
        #pragma unroll
        for (int ct = 0; ct < 8; ++ct) {
            const int col = ct * 16 + lr;
            const float bb = b0[col];
            #pragma unroll
            for (int r = 0; r < 4; ++r) {
                float v = fmaxf(acc[ct][r] + bb, 0.f);
                bufA[(size_t)(orow0 + r) * 128 + col] = f2bf(v);
            }
        }
    } else {
        // ---- gatesPre: g = (relu(Xfb@Wf1+bf1)@Wf2+bf2) * (relu(Xt@Wt1+bt1)@Wt2+bt2) ----
        // Weight pack layout: matrix m at m*2048 short8s: Wf1=3*2048, Wf2=4*2048,
        // Wt1=5*2048, Wt2=6*2048  (R8 bug: used 1024/2048/3072/4096).
        const int blk = blockIdx.x - 1536;
        const int w = tid >> 6, l = tid & 63, lr = l & 15, q = l >> 4;
        const int row0 = blk * 64 + w * 16;
        f32x4 accf[8], acct[8];
        {
            U8 bfrag;
            f32x4 x = *(const f32x4*)(Xfb + (size_t)(row0 + lr) * 16 + 4 * q);
            #pragma unroll
            for (int i = 0; i < 4; ++i) { bfrag.s[i] = (short)f2bf(x[i]); bfrag.s[4+i] = 0; }
            f32x4 s1[8];
            #pragma unroll
            for (int mt = 0; mt < 8; ++mt) {
                s1[mt] = __builtin_amdgcn_mfma_f32_16x16x32_bf16(
                             wfb[6144 + mt * 64 + l], bfrag.v, (f32x4){0.f,0.f,0.f,0.f}, 0, 0, 0);
                f32x4 bb = *(const f32x4*)(bf1v + mt * 16 + 4 * q);
                #pragma unroll
                for (int rr = 0; rr < 4; ++rr) s1[mt][rr] = fmaxf(s1[mt][rr] + bb[rr], 0.f);
            }
            #pragma unroll
            for (int ct = 0; ct < 8; ++ct) accf[ct] = (f32x4){0.f,0.f,0.f,0.f};
            #pragma unroll
            for (int kc = 0; kc < 4; ++kc) {
                U8 af;
                #pragma unroll
                for (int i = 0; i < 8; ++i) af.s[i] = (short)f2bf(s1[2*kc + (i>>2)][i & 3]);
                #pragma unroll
                for (int ct = 0; ct < 8; ++ct)
                    accf[ct] = __builtin_amdgcn_mfma_f32_16x16x32_bf16(
                                   af.v, wfb[8192 + (kc * 8 + ct) * 64 + l], accf[ct], 0, 0, 0);
            }
        }
        {
            U8 bfrag;
            #pragma unroll
            for (int i = 0; i < 8; ++i) bfrag.s[i] = 0;
            if (q < 2) {
                f32x4 x = *(const f32x4*)(Xt + (size_t)(row0 + lr) * 8 + 4 * q);
                #pragma unroll
                for (int i = 0; i < 4; ++i) bfrag.s[i] = (short)f2bf(x[i]);
            }
            f32x4 s1[8];
            #pragma unroll
            for (int mt = 0; mt < 8; ++mt) {
                s1[mt] = __builtin_amdgcn_mfma_f32_16x16x32_bf16(
                             wfb[10240 + mt * 64 + l], bfrag.v, (f32x4){0.f,0.f,0.f,0.f}, 0, 0, 0);
                f32x4 bb = *(const f32x4*)(bt1v + mt * 16 + 4 * q);
                #pragma unroll
                for (int rr = 0; rr < 4; ++rr) s1[mt][rr] = fmaxf(s1[mt][rr] + bb[rr], 0.f);
            }
            #pragma unroll
            for (int ct = 0; ct < 8; ++ct) acct[ct] = (f32x4){0.f,0.f,0.f,0.f};
            #pragma unroll
            for (int kc = 0; kc < 4; ++kc) {
                U8 af;
                #pragma unroll
                for (int i = 0; i < 8; ++i) af.s[i] = (short)f2bf(s1[2*kc + (i>>2)][i & 3]);
                #pragma unroll
                for (int ct = 0; ct < 8; ++ct)
                    acct[ct] = __builtin_amdgcn_mfma_f32_16x16x32_bf16(
                                   af.v, wfb[12288 + (kc * 8 + ct) * 64 + l], acct[ct], 0, 0, 0);
            }
        }
        const int orow0 = row0 + 4 * q;
        #pragma unroll
        for (int ct = 0; ct < 8; ++ct) {
            const int col = ct * 16 + lr;
            const float b2f = bf2v[col];
            const float b2t = bt2v[col];
            #pragma unroll
            for (int rr = 0; rr < 4; ++rr) {
                const size_t idx = (size_t)(orow0 + rr) * 128 + col;
                gbuf[idx] = f2bf((accf[ct][rr] + b2f) * (acct[ct][rr] + b2t));
            }
        }
    }
}

// ================= K4/K5: fused aggregate + MFMA GEMM =================
// Block owns 64 rows: agg into LDS (u64 As[64][33], +1 pad), sync, 64x128 GEMM.
// KW_SIDE=false (layer1): gsrc=h0, epilogue writes xdoc bf16 + out_doc=xdoc*g.
// KW_SIDE=true  (layer2): gsrc=xdoc, adds dk^2*h0, epilogue writes out_kw fp32.
template<bool KW_SIDE>
__global__ __launch_bounds__(256, 6) void agm_k(
        const int* __restrict__ off, const int* __restrict__ cnt,
        const int* __restrict__ csr, const u16* __restrict__ gsrc,
        const u16* __restrict__ h0v, const float* __restrict__ dis,
        const short8* __restrict__ wf, const float* __restrict__ bias,
        const u16* __restrict__ gmul, u16* __restrict__ outbf,
        float* __restrict__ outf32) {
    __shared__ u64 As[64][33];
    __shared__ int soff[64], scnt[64];
    __shared__ float sdis[64];
    const int tid = threadIdx.x;
    const int r0 = blockIdx.x * 64;
    if (tid < 64) {
        int seg = KW_SIDE ? (r0 + tid) : (NKW + r0 + tid);
        soff[tid] = off[seg];
        scnt[tid] = cnt[seg];
        sdis[tid] = dis[seg];
    }
    __syncthreads();

    const int g8 = tid >> 5, lane = tid & 31;
    #define ACC4(vv) { a0 += bf2f((u16)(vv)); a1 += bf2f((u16)((vv) >> 16)); \
                       a2 += bf2f((u16)((vv) >> 32)); a3 += bf2f((u16)((vv) >> 48)); }
    for (int it = 0; it < 8; ++it) {
        const int lr = it * 8 + g8;
        const int st = soff[lr], n = scnt[lr];
        float a0 = 0.f, a1 = 0.f, a2 = 0.f, a3 = 0.f;
        int i = 0;
        for (; i + 8 <= n; i += 8) {
            int nb[8];
            #pragma unroll
            for (int k = 0; k < 8; ++k) nb[k] = __builtin_nontemporal_load(csr + st + i + k);
            u64 v[8];
            #pragma unroll
            for (int k = 0; k < 8; ++k)
                v[k] = *(const u64*)(gsrc + (size_t)nb[k] * 128 + lane * 4);
            #pragma unroll
            for (int k = 0; k < 8; ++k) ACC4(v[k])
        }
        for (; i < n; ++i) {
            int nb = __builtin_nontemporal_load(csr + st + i);
            u64 v = *(const u64*)(gsrc + (size_t)nb * 128 + lane * 4);
            ACC4(v)
        }
        const float dk = sdis[lr];
        if (KW_SIDE) {
            u64 h = *(const u64*)(h0v + (size_t)(r0 + lr) * 128 + lane * 4);
            a0 = dk * (a0 + dk * bf2f((u16)h));
            a1 = dk * (a1 + dk * bf2f((u16)(h >> 16)));
            a2 = dk * (a2 + dk * bf2f((u16)(h >> 32)));
            a3 = dk * (a3 + dk * bf2f((u16)(h >> 48)));
        } else {
            a0 *= dk; a1 *= dk; a2 *= dk; a3 *= dk;
        }
        As[lr][lane] = (u64)f2bf(a0) | ((u64)f2bf(a1) << 16) |
                       ((u64)f2bf(a2) << 32) | ((u64)f2bf(a3) << 48);
    }
    #undef ACC4
    __syncthreads();

    // ---- GEMM phase ----
    const int w = tid >> 6, l = tid & 63, lr2 = l & 15, q = l >> 4;
    f32x4 acc[8];
    #pragma unroll
    for (int ct = 0; ct < 8; ++ct) acc[ct] = (f32x4){0.f, 0.f, 0.f, 0.f};
    #pragma unroll
    for (int kc = 0; kc < 4; ++kc) {
        U8 a;
        a.u[0] = As[w * 16 + lr2][8 * kc + q];
        a.u[1] = As[w * 16 + lr2][8 * kc + q + 4];
        #pragma unroll
        for (int ct = 0; ct < 8; ++ct)
            acc[ct] = __builtin_amdgcn_mfma_f32_16x16x32_bf16(
                          a.v, wf[(kc * 8 + ct) * 64 + l], acc[ct], 0, 0, 0);
    }
    const int orow0 = w * 16 + 4 * q;
    #pragma unroll
    for (int ct = 0; ct < 8; ++ct) {
        const int col = ct * 16 + lr2;
        const float bb = bias[col];
        #pragma unroll
        for (int r = 0; r < 4; ++r) {
            float v = fmaxf(acc[ct][r] + bb, 0.f);
            const size_t idx = (size_t)(r0 + orow0 + r) * 128 + col;
            if (KW_SIDE) {
                __builtin_nontemporal_store(v, outf32 + idx);
            } else {
                u16 xv = f2bf(v);
                outbf[idx] = xv;
                float o = bf2f(xv) * bf2f(gmul[idx]);
                __builtin_nontemporal_store(o, outf32 + idx);
            }
        }
    }
}

extern "C" void kernel_launch(void* const* d_in, const int* in_sizes, int n_in,
                              void* d_out, int out_size, void* d_ws, size_t ws_size,
                              hipStream_t stream) {
    const float* Xn  = (const float*)d_in[0];
    const float* Xfb = (const float*)d_in[1];
    const float* Xt  = (const float*)d_in[2];
    const int*   e01 = (const int*)d_in[3];
    const float* W0  = (const float*)d_in[6];
    const float* b0  = (const float*)d_in[7];
    const float* Wg1 = (const float*)d_in[8];
    const float* bg1 = (const float*)d_in[9];
    const float* Wg2 = (const float*)d_in[10];
    const float* bg2 = (const float*)d_in[11];
    const float* Wf1 = (const float*)d_in[12];
    const float* bf1 = (const float*)d_in[13];
    const float* Wf2 = (const float*)d_in[14];
    const float* bf2 = (const float*)d_in[15];
    const float* Wt1 = (const float*)d_in[16];
    const float* bt1 = (const float*)d_in[17];
    const float* Wt2 = (const float*)d_in[18];
    const float* bt2 = (const float*)d_in[19];

    float* out = (float*)d_out;
    char*  ws  = (char*)d_ws;
    u16*   bufA  = (u16*)(ws + BUFA_OFF);     // h0 bf16
    u16*   bufB  = (u16*)(ws + BUFB_OFF);     // g = xf*xt bf16
    u16*   bufC  = (u16*)(ws + BUFC_OFF);     // pairs, then xdoc bf16
    u32*   pairs = (u32*)(ws + BUFC_OFF);
    short8* wfb  = (short8*)(ws + WF_OFF);
    int*   csr   = (int*)(ws + CSR_OFF);
    int*   cnt   = (int*)(ws + CNT_OFF);
    int*   bhist = (int*)(ws + AUX_OFF);
    int*   bfill = bhist + 512;
    int*   off   = (int*)(ws + OFF_OFF);
    float* dis   = (float*)(ws + DIS_OFF);

    const int* src = e01;
    const int* dst = e01 + NE;

    PrepArgs pa;
    pa.w[0] = W0;  pa.K[0] = 128;
    pa.w[1] = Wg1; pa.K[1] = 128;
    pa.w[2] = Wg2; pa.K[2] = 128;
    pa.w[3] = Wf1; pa.K[3] = 16;
    pa.w[4] = Wf2; pa.K[4] = 128;
    pa.w[5] = Wt1; pa.K[5] = 8;
    pa.w[6] = Wt2; pa.K[6] = 128;

    hipMemsetAsync(bhist, 0, 4096, stream);                       // bhist + bfill
    k1_hist_prep<<<NBLK + 56, 256, 0, stream>>>(src, dst, bhist, pa, wfb);
    k2_part<<<NBLK, 256, 0, stream>>>(src, dst, bhist, bfill, pairs);
    k3_build_gemm_gates<<<2560, 256, 0, stream>>>(
        pairs, bhist, off, cnt, dis, csr,
        Xn, wfb, b0, bufA,
        Xfb, Xt, bf1, bf2, bt1, bt2, bufB);
    // layer 1 fused: agg(h0) -> GEMM Wg1 -> xdoc bf16 + out_doc = xdoc*g
    agm_k<false><<<NDOC / 64, 256, 0, stream>>>(
        off, cnt, csr, bufA, nullptr, dis,
        wfb + 1 * 2048, bg1, bufB, bufC, out + (size_t)NKW * 128);
    // layer 2 fused: agg(xdoc) + dk^2*h0 -> GEMM Wg2 -> out_kw fp32
    agm_k<true><<<NKW / 64, 256, 0, stream>>>(
        off, cnt, csr, bufC, bufA, dis,
        wfb + 2 * 2048, bg2, nullptr, nullptr, out);
}

// Round 10
// 205.711 us; speedup vs baseline: 1.1607x; 1.1607x over previous
//
#include <hip/hip_runtime.h>

#define NKW   65536
#define NDOC  65536
#define NSEG  131072
#define NE    1048576
#define CHUNK 4096
#define NBLK  (NE / CHUNK)    // 256

typedef unsigned long long u64;
typedef unsigned short     u16;
typedef unsigned int       u32;

typedef __attribute__((ext_vector_type(8))) short short8;   // 8 bf16
typedef __attribute__((ext_vector_type(4))) float f32x4;    // MFMA acc

union U8 { short8 v; u64 u[2]; short s[8]; };

__device__ __forceinline__ u16 f2bf(float f) {              // RNE f32->bf16
    u32 u = __builtin_bit_cast(u32, f);
    u = (u + 0x7fffu + ((u >> 16) & 1u)) >> 16;
    return (u16)u;
}
__device__ __forceinline__ float bf2f(u16 h) {
    return __builtin_bit_cast(float, (u32)h << 16);
}

// ---------------- workspace layout (bytes) ----------------
// bufA: h0 bf16 (agg2 writes in-place). bufB: g = xf*xt bf16.
// bufC: pairs (CSR build), then agg1-out -> xdoc bf16 (mgemm1 in-place).
#define BUFA_OFF 0ull
#define BUFB_OFF 16777216ull
#define BUFC_OFF 33554432ull
#define WF_OFF   50331648ull            // 7 * 32KB fragment-packed weights
#define CSR_OFF  51380224ull            // 2*NE ints = 8 MB
#define CNT_OFF  59768832ull            // NSEG ints
#define AUX_OFF  60293120ull            // bhist[512] | bfill[512]
#define OFF_OFF  60821504ull            // NSEG ints
#define DIS_OFF  61345792ull            // NSEG floats

struct PrepArgs { const float* w[7]; int K[7]; };

// ================= K1: bucket histogram (blocks 0..255) + weight pre-pack =======
__global__ __launch_bounds__(256) void k1_hist_prep(
        const int* __restrict__ src, const int* __restrict__ dst,
        int* __restrict__ bhist, PrepArgs pa, short8* __restrict__ wfb) {
    __shared__ int h[512];
    const int tid = threadIdx.x;
    if (blockIdx.x < NBLK) {
        for (int i = tid; i < 512; i += 256) h[i] = 0;
        __syncthreads();
        int e0 = blockIdx.x * CHUNK;
        for (int i = tid; i < CHUNK; i += 256) {
            int s = src[e0 + i];
            int d = dst[e0 + i] - NKW;
            atomicAdd(&h[s >> 8], 1);
            atomicAdd(&h[256 + (d >> 8)], 1);
        }
        __syncthreads();
        for (int i = tid; i < 512; i += 256)
            if (h[i]) atomicAdd(&bhist[i], h[i]);
    } else {
        int u = (blockIdx.x - NBLK) * 4 + (tid >> 6);   // prepw unit 0..223
        if (u < 224) {
            int m = u >> 5, bk = u & 31;
            int kc = bk >> 3, ct = bk & 7;
            int l = tid & 63;
            int K = pa.K[m];
            const float* W = pa.w[m];
            U8 o;
            #pragma unroll
            for (int i = 0; i < 8; ++i) {
                int k   = kc * 32 + 4 * (l >> 4) + (i & 3) + 16 * (i >> 2);
                int col = ct * 16 + (l & 15);
                float v = (k < K) ? W[(size_t)k * 128 + col] : 0.f;
                o.s[i] = (short)f2bf(v);
            }
            wfb[(size_t)m * 2048 + bk * 64 + l] = o.v;
        }
    }
}

// ================= K2: edge partition (inline global-base scan) =================
__global__ __launch_bounds__(256) void k2_part(
        const int* __restrict__ src, const int* __restrict__ dst,
        const int* __restrict__ bhist, int* __restrict__ bfill,
        u32* __restrict__ pairs) {
    __shared__ int h[512], sc[512], base[512], gb[512];
    __shared__ u32 staged[2 * CHUNK];
    const int tid = threadIdx.x;

    for (int i = tid; i < 512; i += 256) gb[i] = bhist[i];
    __syncthreads();
    for (int d = 1; d < 512; d <<= 1) {
        int i1 = tid + 256;
        int t0 = (tid >= d) ? gb[tid - d] : 0;
        int t1 = gb[i1 - d];
        __syncthreads();
        gb[tid] += t0; gb[i1] += t1;
        __syncthreads();
    }
    for (int i = tid; i < 512; i += 256) gb[i] -= bhist[i];   // exclusive base
    for (int i = tid; i < 512; i += 256) h[i] = 0;
    __syncthreads();

    const int e0 = blockIdx.x * CHUNK;
    int se[16], de[16];
    #pragma unroll
    for (int j = 0; j < 16; ++j) {
        int e = e0 + tid + j * 256;
        se[j] = src[e];
        de[j] = dst[e] - NKW;
        atomicAdd(&h[se[j] >> 8], 1);
        atomicAdd(&h[256 + (de[j] >> 8)], 1);
    }
    __syncthreads();

    sc[tid] = h[tid];
    __syncthreads();
    for (int d = 1; d < 256; d <<= 1) {
        int t = (tid >= d) ? sc[tid - d] : 0;
        __syncthreads();
        sc[tid] += t;
        __syncthreads();
    }
    sc[256 + tid] = h[256 + tid];
    __syncthreads();
    for (int d = 1; d < 256; d <<= 1) {
        int t = (tid >= d) ? sc[256 + tid - d] : 0;
        __syncthreads();
        sc[256 + tid] += t;
        __syncthreads();
    }

    for (int i = tid; i < 512; i += 256) {
        base[i] = gb[i] + atomicAdd(&bfill[i], h[i]);
        sc[i] -= h[i];
        h[i] = 0;
    }
    __syncthreads();

    #pragma unroll
    for (int j = 0; j < 16; ++j) {
        int bk = se[j] >> 8;
        int r  = atomicAdd(&h[bk], 1);
        staged[sc[bk] + r] = ((u32)(se[j] & 255) << 16) | (u32)de[j];
        int bd = 256 + (de[j] >> 8);
        int r2 = atomicAdd(&h[bd], 1);
        staged[CHUNK + sc[bd] + r2] = ((u32)(de[j] & 255) << 16) | (u32)se[j];
    }
    __syncthreads();

    for (int i = tid; i < 512; i += 256) {
        int n = h[i];
        int so = (i < 256 ? 0 : CHUNK) + sc[i];
        u32* dp = pairs + base[i];
        for (int j = 0; j < n; ++j) dp[j] = staged[so + j];
    }
}

// ================= K3: CSR build (0..511) | mgemm0 (512..1535) | gatesPre =======
__global__ __launch_bounds__(256, 4) void k3_build_gemm_gates(
        const u32* __restrict__ pairs, const int* __restrict__ bhist,
        int* __restrict__ off, int* __restrict__ cnt, float* __restrict__ dis,
        int* __restrict__ csr,
        const float* __restrict__ Xn, const short8* __restrict__ wfb,
        const float* __restrict__ b0, u16* __restrict__ bufA,
        const float* __restrict__ Xfb, const float* __restrict__ Xt,
        const float* __restrict__ bf1v, const float* __restrict__ bf2v,
        const float* __restrict__ bt1v, const float* __restrict__ bt2v,
        u16* __restrict__ gbuf) {
    __shared__ int S[2816];    // lcnt[1024] | loff[1024] | bs[256] | gsc[512]
    const int tid = threadIdx.x;

    if (blockIdx.x < 512) {
        int* lcnt = S;
        int* loff = S + 1024;
        int* bs   = S + 2048;
        int* gsc  = S + 2304;
        const int b = blockIdx.x;
        for (int i = tid; i < 512; i += 256) gsc[i] = bhist[i];
        __syncthreads();
        for (int d = 1; d < 512; d <<= 1) {
            int i1 = tid + 256;
            int t0 = (tid >= d) ? gsc[tid - d] : 0;
            int t1 = gsc[i1 - d];
            __syncthreads();
            gsc[tid] += t0; gsc[i1] += t1;
            __syncthreads();
        }
        const int size  = bhist[b];
        const int start = gsc[b] - size;      // exclusive
        for (int i = tid; i < 1024; i += 256) lcnt[i] = 0;
        __syncthreads();
        for (int i = tid; i < size; i += 256) {
            u32 p = __builtin_nontemporal_load(pairs + start + i);
            atomicAdd(&lcnt[(p >> 16) & 255], 1);
        }
        __syncthreads();
        int s = lcnt[tid];
        bs[tid] = s;
        __syncthreads();
        for (int d = 1; d < 256; d <<= 1) {
            int t = (tid >= d) ? bs[tid - d] : 0;
            __syncthreads();
            bs[tid] += t;
            __syncthreads();
        }
        const int P = bs[tid] - s;
        const int seg = (b < 256) ? (b * 256 + tid) : (NKW + (b - 256) * 256 + tid);
        off[seg] = start + P;
        cnt[seg] = s;
        dis[seg] = rsqrtf((float)(s + 1));
        loff[tid] = P;
        lcnt[tid] = 0;
        __syncthreads();
        for (int i = tid; i < size; i += 256) {
            u32 p = __builtin_nontemporal_load(pairs + start + i);
            int key = (p >> 16) & 255;
            int r = atomicAdd(&lcnt[key], 1);
            csr[start + loff[key] + r] = (int)(p & 0xFFFF);
        }
    } else if (blockIdx.x < 1536) {
        // ---- layer 0: h0 = relu(Xn @ W0 + b0), fp32 in, bf16 out ----
        const int blk = blockIdx.x - 512;
        const int w = tid >> 6, l = tid & 63, lr = l & 15, q = l >> 4;
        const int row = blk * 64 + w * 16 + lr;
        f32x4 acc[8];
        #pragma unroll
        for (int ct = 0; ct < 8; ++ct) acc[ct] = (f32x4){0.f, 0.f, 0.f, 0.f};
        #pragma unroll
        for (int kc = 0; kc < 4; ++kc) {
            U8 a;
            const int kb = kc * 32 + 4 * q;
            const float* A = Xn + (size_t)row * 128;
            f32x4 lo = *(const f32x4*)(A + kb);
            f32x4 hi = *(const f32x4*)(A + kb + 16);
            #pragma unroll
            for (int i = 0; i < 4; ++i) {
                a.s[i]     = (short)f2bf(lo[i]);
                a.s[4 + i] = (short)f2bf(hi[i]);
            }
            #pragma unroll
            for (int ct = 0; ct < 8; ++ct)
                acc[ct] = __builtin_amdgcn_mfma_f32_16x16x32_bf16(
                              a.v, wfb[(kc * 8 + ct) * 64 + l], acc[ct], 0, 0, 0);
        }
        const int orow0 = blk * 64 + w * 16 + 4 * q;
        #pragma unroll
        for (int ct = 0; ct < 8; ++ct) {
            const int col = ct * 16 + lr;
            const float bb = b0[col];
            #pragma unroll
            for (int r = 0; r < 4; ++r) {
                float v = fmaxf(acc[ct][r] + bb, 0.f);
                bufA[(size_t)(orow0 + r) * 128 + col] = f2bf(v);
            }
        }
    } else {
        // ---- gatesPre: g = (relu(Xfb@Wf1+bf1)@Wf2+bf2) * (relu(Xt@Wt1+bt1)@Wt2+bt2)
        // pack layout: matrix m at m*2048 short8s: Wf1=6144, Wf2=8192, Wt1=10240, Wt2=12288
        const int blk = blockIdx.x - 1536;
        const int w = tid >> 6, l = tid & 63, lr = l & 15, q = l >> 4;
        const int row0 = blk * 64 + w * 16;
        f32x4 accf[8], acct[8];
        {
            U8 bfrag;
            f32x4 x = *(const f32x4*)(Xfb + (size_t)(row0 + lr) * 16 + 4 * q);
            #pragma unroll
            for (int i = 0; i < 4; ++i) { bfrag.s[i] = (short)f2bf(x[i]); bfrag.s[4+i] = 0; }
            f32x4 s1[8];
            #pragma unroll
            for (int mt = 0; mt < 8; ++mt) {
                s1[mt] = __builtin_amdgcn_mfma_f32_16x16x32_bf16(
                             wfb[6144 + mt * 64 + l], bfrag.v, (f32x4){0.f,0.f,0.f,0.f}, 0, 0, 0);
                f32x4 bb = *(const f32x4*)(bf1v + mt * 16 + 4 * q);
                #pragma unroll
                for (int rr = 0; rr < 4; ++rr) s1[mt][rr] = fmaxf(s1[mt][rr] + bb[rr], 0.f);
            }
            #pragma unroll
            for (int ct = 0; ct < 8; ++ct) accf[ct] = (f32x4){0.f,0.f,0.f,0.f};
            #pragma unroll
            for (int kc = 0; kc < 4; ++kc) {
                U8 af;
                #pragma unroll
                for (int i = 0; i < 8; ++i) af.s[i] = (short)f2bf(s1[2*kc + (i>>2)][i & 3]);
                #pragma unroll
                for (int ct = 0; ct < 8; ++ct)
                    accf[ct] = __builtin_amdgcn_mfma_f32_16x16x32_bf16(
                                   af.v, wfb[8192 + (kc * 8 + ct) * 64 + l], accf[ct], 0, 0, 0);
            }
        }
        {
            U8 bfrag;
            #pragma unroll
            for (int i = 0; i < 8; ++i) bfrag.s[i] = 0;
            if (q < 2) {
                f32x4 x = *(const f32x4*)(Xt + (size_t)(row0 + lr) * 8 + 4 * q);
                #pragma unroll
                for (int i = 0; i < 4; ++i) bfrag.s[i] = (short)f2bf(x[i]);
            }
            f32x4 s1[8];
            #pragma unroll
            for (int mt = 0; mt < 8; ++mt) {
                s1[mt] = __builtin_amdgcn_mfma_f32_16x16x32_bf16(
                             wfb[10240 + mt * 64 + l], bfrag.v, (f32x4){0.f,0.f,0.f,0.f}, 0, 0, 0);
                f32x4 bb = *(const f32x4*)(bt1v + mt * 16 + 4 * q);
                #pragma unroll
                for (int rr = 0; rr < 4; ++rr) s1[mt][rr] = fmaxf(s1[mt][rr] + bb[rr], 0.f);
            }
            #pragma unroll
            for (int ct = 0; ct < 8; ++ct) acct[ct] = (f32x4){0.f,0.f,0.f,0.f};
            #pragma unroll
            for (int kc = 0; kc < 4; ++kc) {
                U8 af;
                #pragma unroll
                for (int i = 0; i < 8; ++i) af.s[i] = (short)f2bf(s1[2*kc + (i>>2)][i & 3]);
                #pragma unroll
                for (int ct = 0; ct < 8; ++ct)
                    acct[ct] = __builtin_amdgcn_mfma_f32_16x16x32_bf16(
                                   af.v, wfb[12288 + (kc * 8 + ct) * 64 + l], acct[ct], 0, 0, 0);
            }
        }
        const int orow0 = row0 + 4 * q;
        #pragma unroll
        for (int ct = 0; ct < 8; ++ct) {
            const int col = ct * 16 + lr;
            const float b2f = bf2v[col];
            const float b2t = bt2v[col];
            #pragma unroll
            for (int rr = 0; rr < 4; ++rr) {
                const size_t idx = (size_t)(orow0 + rr) * 128 + col;
                gbuf[idx] = f2bf((accf[ct][rr] + b2f) * (acct[ct][rr] + b2t));
            }
        }
    }
}

// ================= standalone bf16 aggregation (R6-verified form) =================
// 8 rows/block, 32 lanes/row (full 256B line per edge), 8-deep gather pipeline.
// KW_SIDE: out = dk*(sum + dk*h0[row]) — h0 read/write row-local => in-place OK.
template<bool KW_SIDE>
__global__ __launch_bounds__(256) void aggb_k(
        const int* __restrict__ off, const int* __restrict__ cnt,
        const int* __restrict__ csr, const u16* __restrict__ gsrc,
        const u16* __restrict__ h0, const float* __restrict__ dis,
        u16* __restrict__ outb) {
    int r    = blockIdx.x * 8 + (threadIdx.x >> 5);
    int lane = threadIdx.x & 31;
    int seg  = KW_SIDE ? r : (NKW + r);
    int st = off[seg];
    int n  = cnt[seg];
    float a0 = 0.f, a1 = 0.f, a2 = 0.f, a3 = 0.f;
    #define ACC4(vv) { a0 += bf2f((u16)(vv)); a1 += bf2f((u16)((vv) >> 16)); \
                       a2 += bf2f((u16)((vv) >> 32)); a3 += bf2f((u16)((vv) >> 48)); }
    int i = 0;
    for (; i + 8 <= n; i += 8) {
        int nb[8];
        #pragma unroll
        for (int k = 0; k < 8; ++k) nb[k] = __builtin_nontemporal_load(csr + st + i + k);
        u64 v[8];
        #pragma unroll
        for (int k = 0; k < 8; ++k)
            v[k] = *(const u64*)(gsrc + (size_t)nb[k] * 128 + lane * 4);
        #pragma unroll
        for (int k = 0; k < 8; ++k) ACC4(v[k])
    }
    for (; i < n; ++i) {
        int nb = __builtin_nontemporal_load(csr + st + i);
        u64 v = *(const u64*)(gsrc + (size_t)nb * 128 + lane * 4);
        ACC4(v)
    }
    #undef ACC4
    float dk = dis[seg];
    if (KW_SIDE) {
        u64 h = *(const u64*)(h0 + (size_t)r * 128 + lane * 4);
        a0 = dk * (a0 + dk * bf2f((u16)h));
        a1 = dk * (a1 + dk * bf2f((u16)(h >> 16)));
        a2 = dk * (a2 + dk * bf2f((u16)(h >> 32)));
        a3 = dk * (a3 + dk * bf2f((u16)(h >> 48)));
    } else {
        a0 *= dk; a1 *= dk; a2 *= dk; a3 *= dk;
    }
    u64 ov = (u64)f2bf(a0) | ((u64)f2bf(a1) << 16) |
             ((u64)f2bf(a2) << 32) | ((u64)f2bf(a3) << 48);
    *(u64*)(outb + (size_t)r * 128 + lane * 4) = ov;
}

// ================= MFMA GEMM (in-place safe: block reads only its own rows) =====
// OUTMODE 0: bf16 store. 1: fp32 store. 2: bf16 xdoc store + fp32 xdoc*g store.
template<int OUTMODE, bool RELU>
__global__ __launch_bounds__(256) void mgemm_k(
        const u16* __restrict__ Av, const short8* __restrict__ wf,
        const float* __restrict__ bias, const u16* __restrict__ gmul,
        u16* __restrict__ outbf, float* __restrict__ outf32) {
    const int tid = threadIdx.x;
    const int w  = tid >> 6;
    const int l  = tid & 63;
    const int lr = l & 15;
    const int q  = l >> 4;
    const int row = blockIdx.x * 64 + w * 16 + lr;

    f32x4 acc[8];
    #pragma unroll
    for (int ct = 0; ct < 8; ++ct) acc[ct] = (f32x4){0.f, 0.f, 0.f, 0.f};

    #pragma unroll
    for (int kc = 0; kc < 4; ++kc) {
        U8 a;
        const int kb = kc * 32 + 4 * q;
        const u16* A = Av + (size_t)row * 128;
        a.u[0] = *(const u64*)(A + kb);
        a.u[1] = *(const u64*)(A + kb + 16);
        #pragma unroll
        for (int ct = 0; ct < 8; ++ct)
            acc[ct] = __builtin_amdgcn_mfma_f32_16x16x32_bf16(
                          a.v, wf[(kc * 8 + ct) * 64 + l], acc[ct], 0, 0, 0);
    }

    const int orow0 = blockIdx.x * 64 + w * 16 + 4 * q;
    #pragma unroll
    for (int ct = 0; ct < 8; ++ct) {
        const int col = ct * 16 + lr;
        const float bb = bias[col];
        #pragma unroll
        for (int r = 0; r < 4; ++r) {
            float v = acc[ct][r] + bb;
            if (RELU) v = fmaxf(v, 0.f);
            const size_t idx = (size_t)(orow0 + r) * 128 + col;
            if (OUTMODE == 0) {
                outbf[idx] = f2bf(v);
            } else if (OUTMODE == 1) {
                __builtin_nontemporal_store(v, outf32 + idx);
            } else {
                u16 xv = f2bf(v);
                outbf[idx] = xv;
                float o = bf2f(xv) * bf2f(gmul[idx]);
                __builtin_nontemporal_store(o, outf32 + idx);
            }
        }
    }
}

extern "C" void kernel_launch(void* const* d_in, const int* in_sizes, int n_in,
                              void* d_out, int out_size, void* d_ws, size_t ws_size,
                              hipStream_t stream) {
    const float* Xn  = (const float*)d_in[0];
    const float* Xfb = (const float*)d_in[1];
    const float* Xt  = (const float*)d_in[2];
    const int*   e01 = (const int*)d_in[3];
    const float* W0  = (const float*)d_in[6];
    const float* b0  = (const float*)d_in[7];
    const float* Wg1 = (const float*)d_in[8];
    const float* bg1 = (const float*)d_in[9];
    const float* Wg2 = (const float*)d_in[10];
    const float* bg2 = (const float*)d_in[11];
    const float* Wf1 = (const float*)d_in[12];
    const float* bf1 = (const float*)d_in[13];
    const float* Wf2 = (const float*)d_in[14];
    const float* bf2 = (const float*)d_in[15];
    const float* Wt1 = (const float*)d_in[16];
    const float* bt1 = (const float*)d_in[17];
    const float* Wt2 = (const float*)d_in[18];
    const float* bt2 = (const float*)d_in[19];

    float* out = (float*)d_out;
    char*  ws  = (char*)d_ws;
    u16*   bufA  = (u16*)(ws + BUFA_OFF);     // h0 bf16; agg2 in-place
    u16*   bufB  = (u16*)(ws + BUFB_OFF);     // g = xf*xt bf16
    u16*   bufC  = (u16*)(ws + BUFC_OFF);     // pairs -> agg1-out -> xdoc bf16
    u32*   pairs = (u32*)(ws + BUFC_OFF);
    short8* wfb  = (short8*)(ws + WF_OFF);
    int*   csr   = (int*)(ws + CSR_OFF);
    int*   cnt   = (int*)(ws + CNT_OFF);
    int*   bhist = (int*)(ws + AUX_OFF);
    int*   bfill = bhist + 512;
    int*   off   = (int*)(ws + OFF_OFF);
    float* dis   = (float*)(ws + DIS_OFF);

    const int* src = e01;
    const int* dst = e01 + NE;

    PrepArgs pa;
    pa.w[0] = W0;  pa.K[0] = 128;
    pa.w[1] = Wg1; pa.K[1] = 128;
    pa.w[2] = Wg2; pa.K[2] = 128;
    pa.w[3] = Wf1; pa.K[3] = 16;
    pa.w[4] = Wf2; pa.K[4] = 128;
    pa.w[5] = Wt1; pa.K[5] = 8;
    pa.w[6] = Wt2; pa.K[6] = 128;

    hipMemsetAsync(bhist, 0, 4096, stream);                       // bhist + bfill
    k1_hist_prep<<<NBLK + 56, 256, 0, stream>>>(src, dst, bhist, pa, wfb);
    k2_part<<<NBLK, 256, 0, stream>>>(src, dst, bhist, bfill, pairs);
    k3_build_gemm_gates<<<2560, 256, 0, stream>>>(
        pairs, bhist, off, cnt, dis, csr,
        Xn, wfb, b0, bufA,
        Xfb, Xt, bf1, bf2, bt1, bt2, bufB);

    // layer 1: agg(h0) -> bufC; GEMM Wg1 in-place -> xdoc bf16 + out_doc = xdoc*g
    aggb_k<false><<<NDOC / 8, 256, 0, stream>>>(off, cnt, csr, bufA, nullptr, dis, bufC);
    mgemm_k<2, true><<<1024, 256, 0, stream>>>(bufC, wfb + 1 * 2048, bg1, bufB,
                                               bufC, out + (size_t)NKW * 128);

    // layer 2: agg(xdoc) + dk^2*h0 -> bufA in-place; GEMM Wg2 -> out_kw fp32
    aggb_k<true><<<NKW / 8, 256, 0, stream>>>(off, cnt, csr, bufC, bufA, dis, bufA);
    mgemm_k<1, true><<<1024, 256, 0, stream>>>(bufA, wfb + 2 * 2048, bg2, nullptr,
                                               nullptr, out);
}